// Round 1
// baseline (1841.471 us; speedup 1.0000x reference)
//
#include <hip/hip_runtime.h>
#include <math.h>

#define V 64
#define TMAX 2048
#define ED 512
#define H 64
#define G3 192

// ---------------- K0: zero the persistent hidden state ----------------
__global__ void k_init(float* __restrict__ h) {
    int i = blockIdx.x * blockDim.x + threadIdx.x;
    if (i < V * H) h[i] = 0.f;
}

// ---------------- K1: xg[v, tl, g] = b_ih[g] + sum_k emb[v,t,k] * W_ih[g,k]
// v2: 128t x 192g block tile, 8t x 12g register micro-tile per thread.
// Per k4: 20 ds_read_b128 feed 384 FMAs (19.2 FMA/read vs 3.84 in v1).
// LDS rows are stride-64 floats (no pad); bank spread comes from an XOR
// column swizzle: E float4-col c stored at c ^ ((row>>3)&7)  (16 rows/wave,
// distinct bank-quads), W at c ^ (row&7) (<=2-way, free).
__global__ __launch_bounds__(256) void k_gemm(
    const float* __restrict__ emb, const int* __restrict__ lengths,
    const float* __restrict__ W_ih, const float* __restrict__ b_ih,
    float* __restrict__ xg, int c, int CT) {
    int v   = blockIdx.y;
    int tl0 = blockIdx.x * 128;
    int t0  = c * CT + tl0;
    int len = lengths[v];
    if (t0 >= len) return;  // nothing in this tile is ever read

    __shared__ __align__(16) float Es[128 * 64];  // 32 KB, swizzled
    __shared__ __align__(16) float Ws[G3 * 64];   // 48 KB, swizzled

    int th = threadIdx.x;
    int tb = th & 15;   // t-block: rows tb*8 .. tb*8+7
    int gb = th >> 4;   // g-block: gates gb*12 .. gb*12+11
    int eswz = tb & 7;  // read-side swizzle for this thread's 8 E rows

    float acc[8][12];
#pragma unroll
    for (int i = 0; i < 8; i++)
#pragma unroll
        for (int j = 0; j < 12; j++) acc[i][j] = 0.f;

    const float* ebase = emb + (size_t)(v * TMAX + t0) * ED;

    for (int kc = 0; kc < 8; kc++) {
        // stage E tile: 128x64 floats = 2048 float4, 8 per thread
#pragma unroll
        for (int r = 0; r < 8; r++) {
            int i = th + r * 256;
            int row = i >> 4, pos = i & 15;
            *(float4*)&Es[row * 64 + (pos ^ ((row >> 3) & 7)) * 4] =
                *(const float4*)&ebase[(size_t)row * ED + kc * 64 + pos * 4];
        }
        // stage W tile: 192x64 floats = 3072 float4, 12 per thread
#pragma unroll
        for (int r = 0; r < 12; r++) {
            int i = th + r * 256;
            int row = i >> 4, pos = i & 15;
            *(float4*)&Ws[row * 64 + (pos ^ (row & 7)) * 4] =
                *(const float4*)&W_ih[(size_t)row * ED + kc * 64 + pos * 4];
        }
        __syncthreads();
#pragma unroll 2
        for (int k4 = 0; k4 < 16; k4++) {
            float4 e[8];
#pragma unroll
            for (int i = 0; i < 8; i++)
                e[i] = *(float4*)&Es[(tb * 8 + i) * 64 + (k4 ^ eswz) * 4];
#pragma unroll
            for (int j = 0; j < 12; j++) {
                int g = gb * 12 + j;
                float4 w = *(float4*)&Ws[g * 64 + (k4 ^ (g & 7)) * 4];
#pragma unroll
                for (int i = 0; i < 8; i++)
                    acc[i][j] += e[i].x * w.x + e[i].y * w.y + e[i].z * w.z + e[i].w * w.w;
            }
        }
        __syncthreads();
    }

    float4 bv[3];
#pragma unroll
    for (int j4 = 0; j4 < 3; j4++)
        bv[j4] = *(const float4*)&b_ih[gb * 12 + j4 * 4];

#pragma unroll
    for (int i = 0; i < 8; i++) {
        size_t ob = ((size_t)(v * CT + tl0 + tb * 8 + i)) * G3 + gb * 12;
#pragma unroll
        for (int j4 = 0; j4 < 3; j4++) {
            float4 o;
            o.x = acc[i][j4 * 4 + 0] + bv[j4].x;
            o.y = acc[i][j4 * 4 + 1] + bv[j4].y;
            o.z = acc[i][j4 * 4 + 2] + bv[j4].z;
            o.w = acc[i][j4 * 4 + 3] + bv[j4].w;
            *(float4*)&xg[ob + j4 * 4] = o;
        }
    }
}

// ---------------- K1s: small-CT fallback (original 32x192 tile) ----------------
__global__ __launch_bounds__(256) void k_gemm_s(
    const float* __restrict__ emb, const int* __restrict__ lengths,
    const float* __restrict__ W_ih, const float* __restrict__ b_ih,
    float* __restrict__ xg, int c, int CT) {
    int v   = blockIdx.y;
    int tl0 = blockIdx.x * 32;
    int t0  = c * CT + tl0;
    int len = lengths[v];
    if (t0 >= len) return;

    __shared__ __align__(16) float Es[32][68];
    __shared__ __align__(16) float Ws[G3][68];

    int th = threadIdx.x;
    int tq = th & 31;
    int gq = th >> 5;

    float acc[24];
#pragma unroll
    for (int j = 0; j < 24; j++) acc[j] = 0.f;

    for (int kc = 0; kc < 8; kc++) {
#pragma unroll
        for (int r = 0; r < 2; r++) {
            int i = th + r * 256;
            int row = i >> 4, pos = i & 15;
            *(float4*)&Es[row][pos * 4] =
                *(const float4*)&emb[((size_t)(v * TMAX + t0 + row)) * ED + kc * 64 + pos * 4];
        }
#pragma unroll
        for (int r = 0; r < 12; r++) {
            int i = th + r * 256;
            int row = i >> 4, pos = i & 15;
            *(float4*)&Ws[row][pos * 4] =
                *(const float4*)&W_ih[(size_t)row * ED + kc * 64 + pos * 4];
        }
        __syncthreads();
#pragma unroll
        for (int k4 = 0; k4 < 16; k4++) {
            float4 e4 = *(float4*)&Es[tq][k4 * 4];
#pragma unroll
            for (int j = 0; j < 24; j++) {
                float4 w4 = *(float4*)&Ws[gq * 24 + j][k4 * 4];
                acc[j] += e4.x * w4.x + e4.y * w4.y + e4.z * w4.z + e4.w * w4.w;
            }
        }
        __syncthreads();
    }

    size_t ob = ((size_t)(v * CT + tl0 + tq)) * G3 + gq * 24;
#pragma unroll
    for (int j4 = 0; j4 < 6; j4++) {
        float4 o;
        o.x = acc[j4 * 4 + 0] + b_ih[gq * 24 + j4 * 4 + 0];
        o.y = acc[j4 * 4 + 1] + b_ih[gq * 24 + j4 * 4 + 1];
        o.z = acc[j4 * 4 + 2] + b_ih[gq * 24 + j4 * 4 + 2];
        o.w = acc[j4 * 4 + 3] + b_ih[gq * 24 + j4 * 4 + 3];
        *(float4*)&xg[ob + j4 * 4] = o;
    }
}

// ---------------- K2: sequential GRU recurrence, one block (3 waves) per var.
// v2: hg accumulation split into 4 independent chains (dep latency 256->~80 cyc)
// and __expf-based activations (saturation-safe) replace libcall expf/tanhf.
__global__ __launch_bounds__(192) void k_rec(
    const float* __restrict__ xg, const int* __restrict__ lengths,
    const float* __restrict__ W_hh, const float* __restrict__ b_hh,
    float* __restrict__ h, int c, int CT) {
    int v  = blockIdx.x;
    int th = threadIdx.x;
    int len = lengths[v];
    int rem = len - c * CT;
    int tcnt = rem < 0 ? 0 : (rem > CT ? CT : rem);

    __shared__ __align__(16) float hs[H];
    __shared__ float znbuf[128];

    float4 w4[16];
#pragma unroll
    for (int k4 = 0; k4 < 16; k4++)
        w4[k4] = *(const float4*)&W_hh[(size_t)th * H + k4 * 4];
    float bhh = b_hh[th];

    if (th < H) hs[th] = h[v * H + th];
    __syncthreads();

    const float* xgv = xg + (size_t)v * CT * G3;
    float xr = 0.f, xz = 0.f, xn = 0.f;
    if (th < H && tcnt > 0) {
        xr = xgv[th]; xz = xgv[64 + th]; xn = xgv[128 + th];
    }

    for (int t = 0; t < tcnt; t++) {
        // prefetch next step's xg one iteration ahead (independent of chain)
        float pr = 0.f, pz = 0.f, pn = 0.f;
        if (th < H && t + 1 < tcnt) {
            const float* p = xgv + (size_t)(t + 1) * G3;
            pr = p[th]; pz = p[64 + th]; pn = p[128 + th];
        }
        // 4 independent accumulator chains
        float a0 = 0.f, a1 = 0.f, a2 = 0.f, a3 = 0.f;
#pragma unroll
        for (int k4 = 0; k4 < 4; k4++) {
            float4 h4 = *(float4*)&hs[k4 * 4];
            a0 += w4[k4].x * h4.x + w4[k4].y * h4.y + w4[k4].z * h4.z + w4[k4].w * h4.w;
        }
#pragma unroll
        for (int k4 = 4; k4 < 8; k4++) {
            float4 h4 = *(float4*)&hs[k4 * 4];
            a1 += w4[k4].x * h4.x + w4[k4].y * h4.y + w4[k4].z * h4.z + w4[k4].w * h4.w;
        }
#pragma unroll
        for (int k4 = 8; k4 < 12; k4++) {
            float4 h4 = *(float4*)&hs[k4 * 4];
            a2 += w4[k4].x * h4.x + w4[k4].y * h4.y + w4[k4].z * h4.z + w4[k4].w * h4.w;
        }
#pragma unroll
        for (int k4 = 12; k4 < 16; k4++) {
            float4 h4 = *(float4*)&hs[k4 * 4];
            a3 += w4[k4].x * h4.x + w4[k4].y * h4.y + w4[k4].z * h4.z + w4[k4].w * h4.w;
        }
        float hg = bhh + ((a0 + a1) + (a2 + a3));

        if (th >= H) znbuf[th - H] = hg;
        __syncthreads();
        if (th < H) {
            // sigmoid(x) = 1/(1+exp(-x)); exp overflow -> inf -> rcp -> 0 (safe)
            float r = __fdividef(1.f, 1.f + __expf(-(hg + xr)));
            float z = __fdividef(1.f, 1.f + __expf(-(znbuf[th] + xz)));
            float pre = xn + r * znbuf[64 + th];
            // tanh(x) = 1 - 2/(exp(2x)+1); saturates cleanly to +-1
            float e2 = __expf(2.f * pre);
            float n = 1.f - __fdividef(2.f, e2 + 1.f);
            float hold = hs[th];
            hs[th] = (1.f - z) * n + z * hold;
            xr = pr; xz = pz; xn = pn;
        }
        __syncthreads();
    }
    if (th < H) h[v * H + th] = hs[th];
}

// ---------------- K2F: fully-fused fallback (tiny workspace). Slow but correct.
__global__ __launch_bounds__(192) void k_rec_fused(
    const float* __restrict__ emb, const int* __restrict__ lengths,
    const float* __restrict__ W_ih, const float* __restrict__ b_ih,
    const float* __restrict__ W_hh, const float* __restrict__ b_hh,
    float* __restrict__ h) {
    int v  = blockIdx.x;
    int th = threadIdx.x;
    int len = lengths[v];

    __shared__ __align__(16) float hs[H];
    __shared__ __align__(16) float es[ED];
    __shared__ float znbuf[128];
    __shared__ float xnbuf[64];

    float4 w4[16];
#pragma unroll
    for (int k4 = 0; k4 < 16; k4++)
        w4[k4] = *(const float4*)&W_hh[(size_t)th * H + k4 * 4];
    float bhh = b_hh[th];
    float bih = b_ih[th];
    if (th < H) hs[th] = 0.f;
    const float* ev = emb + (size_t)v * TMAX * ED;
    const float* wrow = W_ih + (size_t)th * ED;

    for (int t = 0; t < len; t++) {
        __syncthreads();
        for (int i = th; i < 128; i += 192)
            *(float4*)&es[i * 4] = *(const float4*)&ev[(size_t)t * ED + i * 4];
        __syncthreads();
        float xgt = bih;
        for (int k4 = 0; k4 < 128; k4++) {
            float4 wv = *(const float4*)&wrow[k4 * 4];
            float4 e4 = *(float4*)&es[k4 * 4];
            xgt += wv.x * e4.x + wv.y * e4.y + wv.z * e4.z + wv.w * e4.w;
        }
        float hg = bhh;
#pragma unroll
        for (int k4 = 0; k4 < 16; k4++) {
            float4 h4 = *(float4*)&hs[k4 * 4];
            hg += w4[k4].x * h4.x + w4[k4].y * h4.y + w4[k4].z * h4.z + w4[k4].w * h4.w;
        }
        if (th >= H && th < 128) znbuf[th - H] = hg + xgt;
        if (th >= 128) { znbuf[th - H] = hg; xnbuf[th - 128] = xgt; }
        __syncthreads();
        if (th < H) {
            float r = 1.f / (1.f + expf(-(hg + xgt)));
            float z = 1.f / (1.f + expf(-znbuf[th]));
            float n = tanhf(xnbuf[th] + r * znbuf[64 + th]);
            float hold = hs[th];
            hs[th] = (1.f - z) * n + z * hold;
        }
    }
    __syncthreads();
    if (th < H) h[v * H + th] = hs[th];
}

// ---------------- K3a: hid[o] = relu(b1[o] + W1[o,:] · concat)
__global__ __launch_bounds__(256) void k_mlp1(
    const float* __restrict__ h, const float* __restrict__ W1,
    const float* __restrict__ b1, float* __restrict__ hid) {
    int o = blockIdx.x, th = threadIdx.x;
    const float* w = W1 + (size_t)o * (V * H);
    float s = 0.f;
#pragma unroll
    for (int r = 0; r < 4; r++) {
        int i = (th + r * 256) * 4;
        float4 a = *(const float4*)&w[i];
        float4 b = *(const float4*)&h[i];
        s += a.x * b.x + a.y * b.y + a.z * b.z + a.w * b.w;
    }
    __shared__ float red[4];
    for (int off = 32; off; off >>= 1) s += __shfl_down(s, off);
    if ((th & 63) == 0) red[th >> 6] = s;
    __syncthreads();
    if (th == 0) {
        float tot = red[0] + red[1] + red[2] + red[3] + b1[o];
        hid[o] = tot > 0.f ? tot : 0.f;
    }
}

// ---------------- K3b: out = b2 + W2 · hid
__global__ void k_mlp2(const float* __restrict__ hid, const float* __restrict__ W2,
                       const float* __restrict__ b2, float* __restrict__ out) {
    int th = threadIdx.x;
    float s = hid[th] * W2[th];
    for (int off = 32; off; off >>= 1) s += __shfl_down(s, off);
    if (th == 0) out[0] = s + b2[0];
}

extern "C" void kernel_launch(void* const* d_in, const int* in_sizes, int n_in,
                              void* d_out, int out_size, void* d_ws, size_t ws_size,
                              hipStream_t stream) {
    const float* emb     = (const float*)d_in[0];
    const int*   lengths = (const int*)d_in[1];
    const float* W_ih    = (const float*)d_in[2];
    const float* W_hh    = (const float*)d_in[3];
    const float* b_ih    = (const float*)d_in[4];
    const float* b_hh    = (const float*)d_in[5];
    const float* W1      = (const float*)d_in[6];
    const float* b1      = (const float*)d_in[7];
    const float* W2      = (const float*)d_in[8];
    const float* b2      = (const float*)d_in[9];
    float* out = (float*)d_out;
    float* wsf = (float*)d_ws;

    const size_t tail = (size_t)V * H + V;  // h + hid (floats)
    int CT = 0;
    const int cts[7] = {2048, 1024, 512, 256, 128, 64, 32};
    for (int i = 0; i < 7; i++) {
        size_t need = ((size_t)V * cts[i] * G3 + tail) * sizeof(float);
        if (need <= ws_size) { CT = cts[i]; break; }
    }

    if (CT > 0) {
        float* xg  = wsf;
        float* hbf = wsf + (size_t)V * CT * G3;
        float* hid = hbf + (size_t)V * H;
        k_init<<<dim3((V * H + 255) / 256), dim3(256), 0, stream>>>(hbf);
        int nch = TMAX / CT;
        for (int c = 0; c < nch; c++) {
            if (CT >= 256)
                k_gemm<<<dim3(CT / 128, V), dim3(256), 0, stream>>>(emb, lengths, W_ih, b_ih, xg, c, CT);
            else
                k_gemm_s<<<dim3(CT / 32, V), dim3(256), 0, stream>>>(emb, lengths, W_ih, b_ih, xg, c, CT);
            k_rec<<<dim3(V), dim3(G3), 0, stream>>>(xg, lengths, W_hh, b_hh, hbf, c, CT);
        }
        k_mlp1<<<dim3(V), dim3(256), 0, stream>>>(hbf, W1, b1, hid);
        k_mlp2<<<dim3(1), dim3(64), 0, stream>>>(hid, W2, b2, out);
    } else {
        float* hbf = wsf;
        float* hid = hbf + (size_t)V * H;
        k_rec_fused<<<dim3(V), dim3(G3), 0, stream>>>(emb, lengths, W_ih, b_ih, W_hh, b_hh, hbf);
        k_mlp1<<<dim3(V), dim3(256), 0, stream>>>(hbf, W1, b1, hid);
        k_mlp2<<<dim3(1), dim3(64), 0, stream>>>(hid, W2, b2, out);
    }
}